// Round 8
// baseline (208.006 us; speedup 1.0000x reference)
//
#include <hip/hip_runtime.h>
#include <math.h>

// ---------------------------------------------------------------------------
// GCN 2-layer forward on MI355X.
// Round 19: de-replicated CSR build. The 8-replica/rank/bases machinery made
// intra-row CSR order deterministic, but consumers SUM rows in fp32 (order
// noise ~1e-7 vs 0.0039 fp8 absmax) - so drop it. hist: single packed[N] u64
// (count<<44 | ewsum), plain atomicAdd, no rank write. fill: rank assigned
// in-place via atomicAdd(&cnt[d],1) - kills 600K random bases reads + 2.4MB
// rank read. scan reads 0.4MB not 3.2MB. Gathers = R16's 8-deep quarter
// layout (best measured: 190.2; R17 octet and R18 depth-16 both regressed).
// ---------------------------------------------------------------------------

typedef unsigned int uint32;
typedef unsigned long long u64;
typedef __attribute__((ext_vector_type(8))) short bf16x8;   // 8 bf16 (4 VGPRs)
typedef __attribute__((ext_vector_type(4))) float f32x4;
typedef __attribute__((ext_vector_type(2))) float f32x2;

__device__ __forceinline__ unsigned short f2bf(float f) {   // RNE fp32->bf16
    uint32 b = __float_as_uint(f);
    return (unsigned short)((b + 0x7FFFu + ((b >> 16) & 1u)) >> 16);
}

// ---------------------------------------------------------------------------
// MFMA GEMM body: H[n x 128] = A[n x 128] @ W (WT bf16 transposed).
// 256 threads = 4 waves; each wave 32 rows x 128 cols (2x8 16x16 tiles),
// K=128 in 4 steps. AFP32: A fp32 (converted inline) vs bf16.
// OUTFP8: D written as fp8 e4m3 bytes vs bf16.
// ---------------------------------------------------------------------------
template <int AFP32, int OUTFP8>
__device__ __forceinline__ void gemm_body(const void* __restrict__ Ap,
                                          const unsigned short* __restrict__ WT,
                                          void* __restrict__ H,
                                          int n, int tb) {
    const int lane = threadIdx.x & 63;
    const int wv   = threadIdx.x >> 6;
    const int quad = lane >> 4;
    const int l16  = lane & 15;
    const int m0   = tb * 128 + wv * 32;
    f32x4 acc[2][8] = {};

    #pragma unroll
    for (int ks = 0; ks < 4; ++ks) {
        const int k0 = ks * 32 + quad * 8;
        bf16x8 a[2];
        #pragma unroll
        for (int rt = 0; rt < 2; ++rt) {
            int row = m0 + rt * 16 + l16;
            if (row >= n) row = n - 1;  // clamp; stores are guarded
            if (AFP32) {
                const float* Af = (const float*)Ap + (size_t)row * 128 + k0;
                float4 f0 = *(const float4*)(Af);
                float4 f1 = *(const float4*)(Af + 4);
                bf16x8 v;
                v[0] = (short)f2bf(f0.x); v[1] = (short)f2bf(f0.y);
                v[2] = (short)f2bf(f0.z); v[3] = (short)f2bf(f0.w);
                v[4] = (short)f2bf(f1.x); v[5] = (short)f2bf(f1.y);
                v[6] = (short)f2bf(f1.z); v[7] = (short)f2bf(f1.w);
                a[rt] = v;
            } else {
                const unsigned short* Ab = (const unsigned short*)Ap + (size_t)row * 128 + k0;
                a[rt] = *(const bf16x8*)Ab;
            }
        }
        #pragma unroll
        for (int ct = 0; ct < 8; ++ct) {
            bf16x8 b = *(const bf16x8*)(WT + (size_t)(ct * 16 + l16) * 128 + k0);
            acc[0][ct] = __builtin_amdgcn_mfma_f32_16x16x32_bf16(a[0], b, acc[0][ct], 0, 0, 0);
            acc[1][ct] = __builtin_amdgcn_mfma_f32_16x16x32_bf16(a[1], b, acc[1][ct], 0, 0, 0);
        }
    }

    // D layout: col = lane&15, row = quad*4 + reg  (m89-verified)
    #pragma unroll
    for (int rt = 0; rt < 2; ++rt) {
        #pragma unroll
        for (int r = 0; r < 4; ++r) {
            int row = m0 + rt * 16 + quad * 4 + r;
            if (row < n) {
                if (OUTFP8) {
                    unsigned char* o = (unsigned char*)H + (size_t)row * 128 + l16;
                    #pragma unroll
                    for (int cp = 0; cp < 4; ++cp) {
                        int pk = __builtin_amdgcn_cvt_pk_fp8_f32(
                            acc[rt][2 * cp][r], acc[rt][2 * cp + 1][r], 0, false);
                        o[(2 * cp) * 16]     = (unsigned char)(pk & 0xFF);
                        o[(2 * cp + 1) * 16] = (unsigned char)((pk >> 8) & 0xFF);
                    }
                } else {
                    unsigned short* o = (unsigned short*)H + (size_t)row * 128 + l16;
                    #pragma unroll
                    for (int ct = 0; ct < 8; ++ct)
                        o[ct * 16] = f2bf(acc[rt][ct][r]);
                }
            }
        }
    }
}

// ---------------------------------------------------------------------------
// Init: zero packed[N u64] + cnt[N u32] + done counter; blocks [0,64) also
// transpose+convert W1/W2 to bf16 WT1/WT2.
// ---------------------------------------------------------------------------
__global__ __launch_bounds__(256) void k_init(u64* __restrict__ packed,
                                              int* __restrict__ cnt, int n,
                                              int* __restrict__ done,
                                              const float* __restrict__ W1,
                                              const float* __restrict__ W2,
                                              unsigned short* __restrict__ WT1,
                                              unsigned short* __restrict__ WT2) {
    int idx = blockIdx.x * 256 + threadIdx.x;
    if (idx < n) { packed[idx] = 0ULL; cnt[idx] = 0; }
    if (idx == 0) *done = 0;
    if (blockIdx.x < 64) {
        int j = blockIdx.x * 256 + threadIdx.x;  // 16384 total
        int k = j >> 7, nn = j & 127;
        WT1[nn * 128 + k] = f2bf(W1[k * 128 + nn]);
        WT2[nn * 128 + k] = f2bf(W2[k * 128 + nn]);
    }
}

// ---------------------------------------------------------------------------
// Fused gemm1 + hist: blocks [0,gGemm) compute h8 = fp8(x@W1) (MFMA pipe);
// blocks [gGemm, ...) accumulate the degree histogram: packed[d] +=
// (1<<44) | fixedpoint(ew). Single table, no replica, no rank.
// ---------------------------------------------------------------------------
__global__ __launch_bounds__(256) void k_gemm1_hist(const float* __restrict__ x,
                                                    const unsigned short* __restrict__ WT1,
                                                    unsigned char* __restrict__ h8,
                                                    const int* __restrict__ dst,
                                                    const float* __restrict__ ew,
                                                    u64* __restrict__ packed,
                                                    int E, int N, int gGemm) {
    const int b = blockIdx.x;
    if (b < gGemm) {
        gemm_body<1, 1>(x, WT1, h8, N, b);
        return;
    }
    int i = (b - gGemm) * 256 + threadIdx.x;
    if (i < E) {
        int d = dst[i];
        u64 add = (1ULL << 44) + (u64)(ew[i] * 4294967296.0f);
        atomicAdd(&packed[d], add);
    }
}

// ---------------------------------------------------------------------------
// Scan (one kernel): per-1024-chunk local exclusive scan of counts into
// rowptr, fused decode (dinv), chunk totals release-stored into csums; last
// block (done counter) wave-scans the <=64 totals into exclusive offsets.
// ---------------------------------------------------------------------------
__global__ __launch_bounds__(256) void k_scan(const u64* __restrict__ packed,
                                              float* __restrict__ dinv,
                                              int* __restrict__ rowptr,
                                              int* __restrict__ csums,
                                              int* __restrict__ done, int nNodes) {
    __shared__ int s[256];
    __shared__ int lastFlag;
    const int t = threadIdx.x;
    const int base = blockIdx.x * 1024 + t * 4;
    const int n = nNodes + 1;  // scan domain: N counts + trailing 0
    int v[4];
    #pragma unroll
    for (int u = 0; u < 4; ++u) {
        int idx = base + u;
        int c = 0;
        if (idx < nNodes) {
            const u64 mask = (1ULL << 44) - 1;
            u64 pv = packed[idx];
            c = (int)(pv >> 44);
            float deg = 1.0f + (float)(pv & mask) * (1.0f / 4294967296.0f);
            dinv[idx] = rsqrtf(deg);
        }
        v[u] = c;
    }
    s[t] = v[0] + v[1] + v[2] + v[3];
    __syncthreads();
    #pragma unroll
    for (int off = 1; off < 256; off <<= 1) {
        int x = (t >= off) ? s[t - off] : 0;
        __syncthreads();
        s[t] += x;
        __syncthreads();
    }
    if (t == 255)
        __hip_atomic_store(&csums[blockIdx.x], s[255], __ATOMIC_RELEASE,
                           __HIP_MEMORY_SCOPE_AGENT);
    int e = (t == 0) ? 0 : s[t - 1];
    if (base + 0 < n) rowptr[base + 0] = e;
    if (base + 1 < n) rowptr[base + 1] = e + v[0];
    if (base + 2 < n) rowptr[base + 2] = e + v[0] + v[1];
    if (base + 3 < n) rowptr[base + 3] = e + v[0] + v[1] + v[2];

    // last-block: exclusive scan of the gridDim.x (<=64) chunk totals
    __syncthreads();  // all stores issued (incl. t255's release store)
    if (t == 0) {
        int prev = __hip_atomic_fetch_add(done, 1, __ATOMIC_ACQ_REL,
                                          __HIP_MEMORY_SCOPE_AGENT);
        lastFlag = (prev == (int)gridDim.x - 1);
    }
    __syncthreads();
    if (lastFlag && t < 64) {
        int g = (int)gridDim.x;
        int orig = (t < g) ? __hip_atomic_load(&csums[t], __ATOMIC_ACQUIRE,
                                               __HIP_MEMORY_SCOPE_AGENT)
                           : 0;
        int vv = orig;
        #pragma unroll
        for (int off = 1; off < 64; off <<= 1) {
            int y = __shfl_up(vv, off, 64);
            if (t >= off) vv += y;
        }
        if (t < g) csums[t] = vv - orig;  // exclusive chunk offset
    }
}

// Fill CSR: pos = rowptr_local[d] + csums[d>>10] + atomicAdd(&cnt[d],1).
// Intra-row order is arrival order (nondeterministic) - consumers SUM the
// row in fp32, so order only perturbs ~1e-7, far below the fp8 noise floor.
__global__ __launch_bounds__(256) void k_fill(const int* __restrict__ src,
                                              const int* __restrict__ dst,
                                              const float* __restrict__ ew,
                                              const float* __restrict__ dinv,
                                              const int* __restrict__ rowptr,
                                              const int* __restrict__ csums,
                                              int* __restrict__ cnt,
                                              float2* __restrict__ csr, int e) {
    int i = blockIdx.x * 256 + threadIdx.x;
    if (i < e) {
        int s = src[i], d = dst[i];
        float nrm = dinv[s] * ew[i] * dinv[d];
        int pos = rowptr[d] + csums[d >> 10] + atomicAdd(&cnt[d], 1);
        csr[pos] = make_float2(__int_as_float(s), nrm);
    }
}

// ---------------------------------------------------------------------------
// CSR gather helper: 8-wide fp32 FMA from fp8 (uint2) rows.
// ---------------------------------------------------------------------------
__device__ __forceinline__ void fma8_f8(float* acc, uint2 u, float w) {
    f32x2 f;
    f = __builtin_amdgcn_cvt_pk_f32_fp8((int)u.x, false);
    acc[0] += f[0] * w; acc[1] += f[1] * w;
    f = __builtin_amdgcn_cvt_pk_f32_fp8((int)u.x, true);
    acc[2] += f[0] * w; acc[3] += f[1] * w;
    f = __builtin_amdgcn_cvt_pk_f32_fp8((int)u.y, false);
    acc[4] += f[0] * w; acc[5] += f[1] * w;
    f = __builtin_amdgcn_cvt_pk_f32_fp8((int)u.y, true);
    acc[6] += f[0] * w; acc[7] += f[1] * w;
}

// ---------------------------------------------------------------------------
// Per-quarter CSR edge walk: the 16 lanes of one quarter own one node and
// process 8 edges per iteration (8 broadcast csr loads + 8 random 128 B row
// loads in flight). acc accumulates cols [l*8, l*8+8) in fp32.
// ---------------------------------------------------------------------------
__device__ __forceinline__ void gather_q8(float* acc, const uint2* __restrict__ T,
                                          const float2* __restrict__ csr,
                                          int start, int end, int l) {
    for (int k = start; k < end; k += 8) {
        float2 c[8];
        float w[8];
        uint2 u[8];
        #pragma unroll
        for (int j = 0; j < 8; ++j) {
            int ej = k + j;
            c[j] = csr[ej < end ? ej : end - 1];
            w[j] = (ej < end) ? c[j].y : 0.0f;
        }
        #pragma unroll
        for (int j = 0; j < 8; ++j)
            u[j] = T[(size_t)__float_as_int(c[j].x) * 16 + l];
        #pragma unroll
        for (int j = 0; j < 8; ++j) fma8_f8(acc, u[j], w[j]);
    }
}

// ---------------------------------------------------------------------------
// Layer-1 aggregation: g8 = fp8(relu(agg(h8) + b1)).
// Node-per-quarter: 16 nodes/block (4 waves x 4 quarters). Each quarter reads
// full fp8 rows (uint2 = 8 fp8/lane, 128 B row); no cross-lane reduction;
// all 64 lanes write (uint2 per lane, 4 node-rows per wave).
// ---------------------------------------------------------------------------
__global__ __launch_bounds__(256) void k_ag1(const unsigned char* __restrict__ h8,
                                             const float2* __restrict__ csr,
                                             const int* __restrict__ rowptr,
                                             const int* __restrict__ csums,
                                             const float* __restrict__ dinv,
                                             const float4* __restrict__ bias4,
                                             unsigned char* __restrict__ g8, int N) {
    const int lane = threadIdx.x & 63;
    const int q = lane >> 4, l = lane & 15;
    const int node = blockIdx.x * 16 + (threadIdx.x >> 6) * 4 + q;
    if (node >= N) return;   // lane-divergent ok: no barriers below
    const uint2* H2 = (const uint2*)h8;
    const int start = rowptr[node] + csums[node >> 10];
    const int end   = rowptr[node + 1] + csums[(node + 1) >> 10];
    const float di = dinv[node];

    float acc[8] = {};
    fma8_f8(acc, H2[(size_t)node * 16 + l], di * di);   // self-loop
    gather_q8(acc, H2, csr, start, end, l);

    float4 b0 = bias4[l * 2], b1v = bias4[l * 2 + 1];
    acc[0] += b0.x;  acc[1] += b0.y;  acc[2] += b0.z;  acc[3] += b0.w;
    acc[4] += b1v.x; acc[5] += b1v.y; acc[6] += b1v.z; acc[7] += b1v.w;
    #pragma unroll
    for (int j = 0; j < 8; ++j) acc[j] = fmaxf(acc[j], 0.0f);
    uint2 o;
    int w0 = __builtin_amdgcn_cvt_pk_fp8_f32(acc[0], acc[1], 0, false);
    w0     = __builtin_amdgcn_cvt_pk_fp8_f32(acc[2], acc[3], w0, true);
    int w1 = __builtin_amdgcn_cvt_pk_fp8_f32(acc[4], acc[5], 0, false);
    w1     = __builtin_amdgcn_cvt_pk_fp8_f32(acc[6], acc[7], w1, true);
    o.x = (uint32)w0; o.y = (uint32)w1;
    ((uint2*)g8)[(size_t)node * 16 + l] = o;
}

// ---------------------------------------------------------------------------
// Layer-2 fused aggregate + GEMM + sigmoid (agg is linear: agg(g)@W2 ==
// agg(g@W2)). Block = 256 threads (4 waves) = 16 nodes, node-per-quarter.
// Phase 1: each quarter gathers its node over the fp8 g8 table (no bias/act),
// all lanes write bf16 rows into LDS sA[16][136] (pad 8 -> 2-way bank
// conflict = free). Phase 2: each wave computes the 16x32 col-slice of
// sA @ W2 at cols [wv*32,wv*32+32), adds b2, sigmoid, writes fp32 out.
// ---------------------------------------------------------------------------
__global__ __launch_bounds__(256) void k_ag2s(const unsigned char* __restrict__ g8,
                                              const float2* __restrict__ csr,
                                              const int* __restrict__ rowptr,
                                              const int* __restrict__ csums,
                                              const float* __restrict__ dinv,
                                              const float* __restrict__ b2,
                                              const unsigned short* __restrict__ WT2,
                                              float* __restrict__ out, int N) {
    __shared__ unsigned short sA[16][136];
    const int lane = threadIdx.x & 63;
    const int wv   = threadIdx.x >> 6;
    const int q    = lane >> 4;     // quarter (== MFMA quad later)
    const int l    = lane & 15;
    const int nb   = blockIdx.x * 16;
    const int node = nb + wv * 4 + q;
    const uint2* G2 = (const uint2*)g8;

    // ---- phase 1: each quarter gathers its node (no bias, no act) ----
    float acc[8] = {};
    if (node < N) {
        const int start = rowptr[node] + csums[node >> 10];
        const int end   = rowptr[node + 1] + csums[(node + 1) >> 10];
        const float di = dinv[node];
        fma8_f8(acc, G2[(size_t)node * 16 + l], di * di);   // self-loop
        gather_q8(acc, G2, csr, start, end, l);
    }
    uint4 o = make_uint4(0u, 0u, 0u, 0u);   // zero rows for node >= N
    if (node < N) {
        o.x = (uint32)f2bf(acc[0]) | ((uint32)f2bf(acc[1]) << 16);
        o.y = (uint32)f2bf(acc[2]) | ((uint32)f2bf(acc[3]) << 16);
        o.z = (uint32)f2bf(acc[4]) | ((uint32)f2bf(acc[5]) << 16);
        o.w = (uint32)f2bf(acc[6]) | ((uint32)f2bf(acc[7]) << 16);
    }
    *(uint4*)&sA[wv * 4 + q][l * 8] = o;

    __syncthreads();

    // ---- phase 2: out[nb..nb+16) = sigmoid(sA @ W2 + b2), cols [wv*32,+32) ----
    f32x4 a2[2] = {};
    #pragma unroll
    for (int ks = 0; ks < 4; ++ks) {
        const int k0 = ks * 32 + q * 8;
        bf16x8 a = *(const bf16x8*)&sA[l][k0];
        #pragma unroll
        for (int ct = 0; ct < 2; ++ct) {
            bf16x8 b = *(const bf16x8*)(WT2 + (size_t)(wv * 32 + ct * 16 + l) * 128 + k0);
            a2[ct] = __builtin_amdgcn_mfma_f32_16x16x32_bf16(a, b, a2[ct], 0, 0, 0);
        }
    }
    // D layout: col (within 16-tile) = lane&15, row = q*4 + reg
    #pragma unroll
    for (int ct = 0; ct < 2; ++ct) {
        const int col = wv * 32 + ct * 16 + l;
        const float bb = b2[col];
        #pragma unroll
        for (int r = 0; r < 4; ++r) {
            int row = nb + q * 4 + r;
            if (row < N) {
                float v = a2[ct][r] + bb;
                out[(size_t)row * 128 + col] = 1.0f / (1.0f + expf(-v));
            }
        }
    }
}

extern "C" void kernel_launch(void* const* d_in, const int* in_sizes, int n_in,
                              void* d_out, int out_size, void* d_ws, size_t ws_size,
                              hipStream_t stream) {
    const float* x  = (const float*)d_in[0];
    const int*   ei = (const int*)d_in[1];
    const float* ew = (const float*)d_in[2];
    const float* W1 = (const float*)d_in[3];
    const float* b1 = (const float*)d_in[4];
    const float* W2 = (const float*)d_in[5];
    const float* b2 = (const float*)d_in[6];

    const int N = in_sizes[0] / 128;
    const int E = in_sizes[2];
    const int* src = ei;
    const int* dst = ei + E;
    float* out = (float*)d_out;

    // Workspace layout (256B-aligned slabs):
    //   dinv [N] | rowptr [N+1] | csums [1024] | done | WT1 | WT2
    //   | csr [E f2] | h8 [N*128 fp8] | g8 [N*128 fp8]
    //   packed u64[N] and cnt u32[N] alias the g8 slab (both dead before
    //   k_ag1 writes g8; packed dead after scan, cnt dead after fill).
    auto align = [](size_t v) { return (v + 255) & ~(size_t)255; };
    char* p = (char*)d_ws;
    float*  dinv   = (float*)p;   p += align((size_t)N * 4);
    int*    rowptr = (int*)p;     p += align((size_t)(N + 1) * 4);
    int*    csums  = (int*)p;     p += align((size_t)1024 * 4);
    int*    done   = (int*)p;     p += align((size_t)256);
    unsigned short* WT1 = (unsigned short*)p; p += align((size_t)128 * 128 * 2);
    unsigned short* WT2 = (unsigned short*)p; p += align((size_t)128 * 128 * 2);
    float2* csr    = (float2*)p;  p += align((size_t)E * 8);
    unsigned char*  h8 = (unsigned char*)p;  p += align((size_t)N * 128);
    unsigned char*  g8 = (unsigned char*)p;
    u64* packed = (u64*)g8;                       // N*8 = 400KB
    int* cnt    = (int*)(g8 + align((size_t)N * 8));  // N*4 = 200KB (within 6.4MB)

    const int nbE = (E + 255) / 256;
    const int gScan = (N + 1 + 1023) / 1024;   // 49 for N=50000 (<=64 required)
    const int gGemm = (N + 127) / 128;
    const int gAg1  = (N + 15) / 16;
    const int gAg2  = (N + 15) / 16;
    const int gInit0 = (N + 255) / 256;        // zero packed+cnt
    const int gInit = gInit0 < 64 ? 64 : gInit0;

    // --- Build (+ layer-1 GEMM overlapped with hist) ---
    k_init<<<gInit, 256, 0, stream>>>(packed, cnt, N, done, W1, W2, WT1, WT2);
    k_gemm1_hist<<<gGemm + nbE, 256, 0, stream>>>(x, WT1, h8, dst, ew, packed,
                                                  E, N, gGemm);
    k_scan<<<gScan, 256, 0, stream>>>(packed, dinv, rowptr, csums, done, N);
    k_fill<<<nbE, 256, 0, stream>>>(src, dst, ew, dinv, rowptr, csums, cnt,
                                    csr, E);

    // --- Layer 1: g8 = fp8(relu(agg(h8) + b1)) ---
    k_ag1<<<gAg1, 256, 0, stream>>>(h8, csr, rowptr, csums, dinv,
                                    (const float4*)b1, g8, N);

    // --- Layer 2 fused: out = sigmoid(agg(g8) @ W2 + b2) ---
    k_ag2s<<<gAg2, 256, 0, stream>>>(g8, csr, rowptr, csums, dinv, b2,
                                     WT2, out, N);
}

// Round 9
// 191.902 us; speedup vs baseline: 1.0839x; 1.0839x over previous
//
#include <hip/hip_runtime.h>
#include <math.h>

// ---------------------------------------------------------------------------
// GCN 2-layer forward on MI355X.
// Round 20: R16 base (replicated-hist build + quarter-per-node 8-deep
// gathers; best measured 190.2) + ONE experiment: k_ag1 split by column
// half with XCD pinning. Block b: node-group b>>1, cols [(b&1)*64,+64).
// With bid%8 XCD round-robin, half=bid&1 is constant per XCD -> each XCD's
// random working set is a 3.2 MB half-table < 4 MiB per-XCD L2 (vs 6.4 MB
// thrashing). Per-edge load = 1 dword/lane (64 B row-half = 1 CL); VALU per
// edge halves. Same accumulation order -> g8 bit-identical. If the XCD
// mapping differs, halves mix -> degrades to R16 behavior (neutral).
// R19's de-replication is reverted (single-table atomics regressed 190->208:
// contention + extra fill atomic round; replicas stay).
// ---------------------------------------------------------------------------

typedef unsigned int uint32;
typedef unsigned long long u64;
typedef __attribute__((ext_vector_type(8))) short bf16x8;   // 8 bf16 (4 VGPRs)
typedef __attribute__((ext_vector_type(4))) float f32x4;
typedef __attribute__((ext_vector_type(2))) float f32x2;

__device__ __forceinline__ unsigned short f2bf(float f) {   // RNE fp32->bf16
    uint32 b = __float_as_uint(f);
    return (unsigned short)((b + 0x7FFFu + ((b >> 16) & 1u)) >> 16);
}

// ---------------------------------------------------------------------------
// MFMA GEMM body: H[n x 128] = A[n x 128] @ W (WT bf16 transposed).
// 256 threads = 4 waves; each wave 32 rows x 128 cols (2x8 16x16 tiles),
// K=128 in 4 steps. AFP32: A fp32 (converted inline) vs bf16.
// OUTFP8: D written as fp8 e4m3 bytes vs bf16.
// ---------------------------------------------------------------------------
template <int AFP32, int OUTFP8>
__device__ __forceinline__ void gemm_body(const void* __restrict__ Ap,
                                          const unsigned short* __restrict__ WT,
                                          void* __restrict__ H,
                                          int n, int tb) {
    const int lane = threadIdx.x & 63;
    const int wv   = threadIdx.x >> 6;
    const int quad = lane >> 4;
    const int l16  = lane & 15;
    const int m0   = tb * 128 + wv * 32;
    f32x4 acc[2][8] = {};

    #pragma unroll
    for (int ks = 0; ks < 4; ++ks) {
        const int k0 = ks * 32 + quad * 8;
        bf16x8 a[2];
        #pragma unroll
        for (int rt = 0; rt < 2; ++rt) {
            int row = m0 + rt * 16 + l16;
            if (row >= n) row = n - 1;  // clamp; stores are guarded
            if (AFP32) {
                const float* Af = (const float*)Ap + (size_t)row * 128 + k0;
                float4 f0 = *(const float4*)(Af);
                float4 f1 = *(const float4*)(Af + 4);
                bf16x8 v;
                v[0] = (short)f2bf(f0.x); v[1] = (short)f2bf(f0.y);
                v[2] = (short)f2bf(f0.z); v[3] = (short)f2bf(f0.w);
                v[4] = (short)f2bf(f1.x); v[5] = (short)f2bf(f1.y);
                v[6] = (short)f2bf(f1.z); v[7] = (short)f2bf(f1.w);
                a[rt] = v;
            } else {
                const unsigned short* Ab = (const unsigned short*)Ap + (size_t)row * 128 + k0;
                a[rt] = *(const bf16x8*)Ab;
            }
        }
        #pragma unroll
        for (int ct = 0; ct < 8; ++ct) {
            bf16x8 b = *(const bf16x8*)(WT + (size_t)(ct * 16 + l16) * 128 + k0);
            acc[0][ct] = __builtin_amdgcn_mfma_f32_16x16x32_bf16(a[0], b, acc[0][ct], 0, 0, 0);
            acc[1][ct] = __builtin_amdgcn_mfma_f32_16x16x32_bf16(a[1], b, acc[1][ct], 0, 0, 0);
        }
    }

    // D layout: col = lane&15, row = quad*4 + reg  (m89-verified)
    #pragma unroll
    for (int rt = 0; rt < 2; ++rt) {
        #pragma unroll
        for (int r = 0; r < 4; ++r) {
            int row = m0 + rt * 16 + quad * 4 + r;
            if (row < n) {
                if (OUTFP8) {
                    unsigned char* o = (unsigned char*)H + (size_t)row * 128 + l16;
                    #pragma unroll
                    for (int cp = 0; cp < 4; ++cp) {
                        int pk = __builtin_amdgcn_cvt_pk_fp8_f32(
                            acc[rt][2 * cp][r], acc[rt][2 * cp + 1][r], 0, false);
                        o[(2 * cp) * 16]     = (unsigned char)(pk & 0xFF);
                        o[(2 * cp + 1) * 16] = (unsigned char)((pk >> 8) & 0xFF);
                    }
                } else {
                    unsigned short* o = (unsigned short*)H + (size_t)row * 128 + l16;
                    #pragma unroll
                    for (int ct = 0; ct < 8; ++ct)
                        o[ct * 16] = f2bf(acc[rt][ct][r]);
                }
            }
        }
    }
}

// ---------------------------------------------------------------------------
// Init: zero packed[8N u64] (as uint4) + done counter; blocks [0,64) also
// transpose+convert W1/W2 to bf16 WT1/WT2.
// ---------------------------------------------------------------------------
__global__ __launch_bounds__(256) void k_init(u64* __restrict__ packed, int n4,
                                              int* __restrict__ done,
                                              const float* __restrict__ W1,
                                              const float* __restrict__ W2,
                                              unsigned short* __restrict__ WT1,
                                              unsigned short* __restrict__ WT2) {
    int idx = blockIdx.x * 256 + threadIdx.x;
    if (idx < n4) ((uint4*)packed)[idx] = make_uint4(0u, 0u, 0u, 0u);
    if (idx == 0) *done = 0;
    if (blockIdx.x < 64) {
        int j = blockIdx.x * 256 + threadIdx.x;  // 16384 total
        int k = j >> 7, nn = j & 127;
        WT1[nn * 128 + k] = f2bf(W1[k * 128 + nn]);
        WT2[nn * 128 + k] = f2bf(W2[k * 128 + nn]);
    }
}

// ---------------------------------------------------------------------------
// Fused gemm1 + hist: blocks [0,gGemm) compute h8 = fp8(x@W1) (MFMA pipe);
// blocks [gGemm, ...) do the 8-replica u64 histogram (atomic/TCC pipe).
// Replica r = (i>>8)&7, rank[i] = per-replica arrival order (atomic return).
// ---------------------------------------------------------------------------
__global__ __launch_bounds__(256) void k_gemm1_hist(const float* __restrict__ x,
                                                    const unsigned short* __restrict__ WT1,
                                                    unsigned char* __restrict__ h8,
                                                    const int* __restrict__ dst,
                                                    const float* __restrict__ ew,
                                                    u64* __restrict__ packed,
                                                    int* __restrict__ rank,
                                                    int E, int N, int gGemm) {
    const int b = blockIdx.x;
    if (b < gGemm) {
        gemm_body<1, 1>(x, WT1, h8, N, b);
        return;
    }
    int i = (b - gGemm) * 256 + threadIdx.x;
    if (i < E) {
        int d = dst[i];
        int r = (i >> 8) & 7;
        u64 add = (1ULL << 44) + (u64)(ew[i] * 4294967296.0f);
        u64 old = atomicAdd(&packed[(size_t)r * N + d], add);
        rank[i] = (int)(old >> 44);
    }
}

// ---------------------------------------------------------------------------
// Scan (one kernel): per-1024-chunk local exclusive scan of total counts into
// rowptr, fused decode (dinv, 8x8-bit replica bases), chunk totals release-
// stored into csums; last block (done counter) wave-scans the <=64 totals
// into exclusive chunk offsets in place.
// ---------------------------------------------------------------------------
__global__ __launch_bounds__(256) void k_scan(const u64* __restrict__ packed,
                                              float* __restrict__ dinv,
                                              u64* __restrict__ bases,
                                              int* __restrict__ rowptr,
                                              int* __restrict__ csums,
                                              int* __restrict__ done, int nNodes) {
    __shared__ int s[256];
    __shared__ int lastFlag;
    const int t = threadIdx.x;
    const int base = blockIdx.x * 1024 + t * 4;
    const int n = nNodes + 1;  // scan domain: N counts + trailing 0
    int v[4];
    #pragma unroll
    for (int u = 0; u < 4; ++u) {
        int idx = base + u;
        int c = 0;
        if (idx < nNodes) {
            const u64 mask = (1ULL << 44) - 1;
            u64 ssum = 0;
            u64 bs = 0;
            uint32 cum = 0;
            #pragma unroll
            for (int r = 0; r < 8; ++r) {
                u64 pv = packed[(size_t)r * nNodes + idx];
                bs |= (u64)cum << (8 * r);  // field 0 = 0
                cum += (uint32)(pv >> 44);
                ssum += (pv & mask);
            }
            c = (int)cum;
            float deg = 1.0f + (float)ssum * (1.0f / 4294967296.0f);
            dinv[idx] = rsqrtf(deg);
            bases[idx] = bs;
        }
        v[u] = c;
    }
    s[t] = v[0] + v[1] + v[2] + v[3];
    __syncthreads();
    #pragma unroll
    for (int off = 1; off < 256; off <<= 1) {
        int x = (t >= off) ? s[t - off] : 0;
        __syncthreads();
        s[t] += x;
        __syncthreads();
    }
    if (t == 255)
        __hip_atomic_store(&csums[blockIdx.x], s[255], __ATOMIC_RELEASE,
                           __HIP_MEMORY_SCOPE_AGENT);
    int e = (t == 0) ? 0 : s[t - 1];
    if (base + 0 < n) rowptr[base + 0] = e;
    if (base + 1 < n) rowptr[base + 1] = e + v[0];
    if (base + 2 < n) rowptr[base + 2] = e + v[0] + v[1];
    if (base + 3 < n) rowptr[base + 3] = e + v[0] + v[1] + v[2];

    // last-block: exclusive scan of the gridDim.x (<=64) chunk totals
    __syncthreads();  // all stores issued (incl. t255's release store)
    if (t == 0) {
        int prev = __hip_atomic_fetch_add(done, 1, __ATOMIC_ACQ_REL,
                                          __HIP_MEMORY_SCOPE_AGENT);
        lastFlag = (prev == (int)gridDim.x - 1);
    }
    __syncthreads();
    if (lastFlag && t < 64) {
        int g = (int)gridDim.x;
        int orig = (t < g) ? __hip_atomic_load(&csums[t], __ATOMIC_ACQUIRE,
                                               __HIP_MEMORY_SCOPE_AGENT)
                           : 0;
        int vv = orig;
        #pragma unroll
        for (int off = 1; off < 64; off <<= 1) {
            int y = __shfl_up(vv, off, 64);
            if (t >= off) vv += y;
        }
        if (t < g) csums[t] = vv - orig;  // exclusive chunk offset
    }
}

// Fill CSR (atomic-free):
//   pos = rowptr_local[d] + csums[d>>10] + base_replica(d, r) + rank[e].
__global__ __launch_bounds__(256) void k_fill(const int* __restrict__ src,
                                              const int* __restrict__ dst,
                                              const float* __restrict__ ew,
                                              const float* __restrict__ dinv,
                                              const int* __restrict__ rowptr,
                                              const int* __restrict__ csums,
                                              const u64* __restrict__ bases,
                                              const int* __restrict__ rank,
                                              float2* __restrict__ csr, int e) {
    int i = blockIdx.x * 256 + threadIdx.x;
    if (i < e) {
        int s = src[i], d = dst[i];
        int r = (i >> 8) & 7;  // must match k_gemm1_hist's replica map
        float nrm = dinv[s] * ew[i] * dinv[d];
        int pos = rowptr[d] + csums[d >> 10]
                + (int)((bases[d] >> (8 * r)) & 0xFF) + rank[i];
        csr[pos] = make_float2(__int_as_float(s), nrm);
    }
}

// ---------------------------------------------------------------------------
// CSR gather helpers: fp32 FMA from fp8 rows (uint2 = 8 fp8 / uint32 = 4 fp8).
// ---------------------------------------------------------------------------
__device__ __forceinline__ void fma8_f8(float* acc, uint2 u, float w) {
    f32x2 f;
    f = __builtin_amdgcn_cvt_pk_f32_fp8((int)u.x, false);
    acc[0] += f[0] * w; acc[1] += f[1] * w;
    f = __builtin_amdgcn_cvt_pk_f32_fp8((int)u.x, true);
    acc[2] += f[0] * w; acc[3] += f[1] * w;
    f = __builtin_amdgcn_cvt_pk_f32_fp8((int)u.y, false);
    acc[4] += f[0] * w; acc[5] += f[1] * w;
    f = __builtin_amdgcn_cvt_pk_f32_fp8((int)u.y, true);
    acc[6] += f[0] * w; acc[7] += f[1] * w;
}

__device__ __forceinline__ void fma4_f8(float* acc, uint32 u, float w) {
    f32x2 f;
    f = __builtin_amdgcn_cvt_pk_f32_fp8((int)u, false);
    acc[0] += f[0] * w; acc[1] += f[1] * w;
    f = __builtin_amdgcn_cvt_pk_f32_fp8((int)u, true);
    acc[2] += f[0] * w; acc[3] += f[1] * w;
}

// ---------------------------------------------------------------------------
// Per-quarter CSR edge walk (full row, uint2/lane): 8 edges per iteration.
// acc accumulates cols [l*8, l*8+8) in fp32.
// ---------------------------------------------------------------------------
__device__ __forceinline__ void gather_q8(float* acc, const uint2* __restrict__ T,
                                          const float2* __restrict__ csr,
                                          int start, int end, int l) {
    for (int k = start; k < end; k += 8) {
        float2 c[8];
        float w[8];
        uint2 u[8];
        #pragma unroll
        for (int j = 0; j < 8; ++j) {
            int ej = k + j;
            c[j] = csr[ej < end ? ej : end - 1];
            w[j] = (ej < end) ? c[j].y : 0.0f;
        }
        #pragma unroll
        for (int j = 0; j < 8; ++j)
            u[j] = T[(size_t)__float_as_int(c[j].x) * 16 + l];
        #pragma unroll
        for (int j = 0; j < 8; ++j) fma8_f8(acc, u[j], w[j]);
    }
}

// ---------------------------------------------------------------------------
// Layer-1 aggregation, XCD-pinned column-split: g8 = fp8(relu(agg(h8)+b1)).
// Block b: node-group b>>1 (16 nodes, quarter-per-node), cols
// [(b&1)*64, +64). With bid%8 XCD round-robin, half=b&1 is constant per XCD
// -> each XCD's random working set is one 3.2 MB half-table (fits 4 MiB L2).
// Each quarter reads one dword/lane per edge (64 B half-row = 1 CL).
// ---------------------------------------------------------------------------
__global__ __launch_bounds__(256) void k_ag1(const unsigned char* __restrict__ h8,
                                             const float2* __restrict__ csr,
                                             const int* __restrict__ rowptr,
                                             const int* __restrict__ csums,
                                             const float* __restrict__ dinv,
                                             const float4* __restrict__ bias4,
                                             unsigned char* __restrict__ g8, int N) {
    const int lane = threadIdx.x & 63;
    const int q = lane >> 4, l = lane & 15;
    const int half = blockIdx.x & 1;
    const int node = (blockIdx.x >> 1) * 16 + (threadIdx.x >> 6) * 4 + q;
    if (node >= N) return;   // lane-divergent ok: no barriers below
    const uint32* H1 = (const uint32*)h8;   // row = 32 dwords
    const int cbase = half * 16 + l;        // dword index within row
    const int start = rowptr[node] + csums[node >> 10];
    const int end   = rowptr[node + 1] + csums[(node + 1) >> 10];
    const float di = dinv[node];

    float acc[4] = {};
    fma4_f8(acc, H1[(size_t)node * 32 + cbase], di * di);   // self-loop
    for (int k = start; k < end; k += 8) {
        float2 c[8];
        float w[8];
        uint32 u[8];
        #pragma unroll
        for (int j = 0; j < 8; ++j) {
            int ej = k + j;
            c[j] = csr[ej < end ? ej : end - 1];
            w[j] = (ej < end) ? c[j].y : 0.0f;
        }
        #pragma unroll
        for (int j = 0; j < 8; ++j)
            u[j] = H1[(size_t)__float_as_int(c[j].x) * 32 + cbase];
        #pragma unroll
        for (int j = 0; j < 8; ++j) fma4_f8(acc, u[j], w[j]);
    }

    float4 bb = bias4[cbase];   // cols [cbase*4, cbase*4+4)
    acc[0] += bb.x; acc[1] += bb.y; acc[2] += bb.z; acc[3] += bb.w;
    #pragma unroll
    for (int j = 0; j < 4; ++j) acc[j] = fmaxf(acc[j], 0.0f);
    int w0 = __builtin_amdgcn_cvt_pk_fp8_f32(acc[0], acc[1], 0, false);
    w0     = __builtin_amdgcn_cvt_pk_fp8_f32(acc[2], acc[3], w0, true);
    ((uint32*)g8)[(size_t)node * 32 + cbase] = (uint32)w0;
}

// ---------------------------------------------------------------------------
// Layer-2 fused aggregate + GEMM + sigmoid (agg is linear: agg(g)@W2 ==
// agg(g@W2)). Block = 256 threads (4 waves) = 16 nodes, node-per-quarter.
// Phase 1: each quarter gathers its node over the fp8 g8 table (no bias/act),
// all lanes write bf16 rows into LDS sA[16][136] (pad 8 -> 2-way bank
// conflict = free). Phase 2: each wave computes the 16x32 col-slice of
// sA @ W2 at cols [wv*32,wv*32+32), adds b2, sigmoid, writes fp32 out.
// ---------------------------------------------------------------------------
__global__ __launch_bounds__(256) void k_ag2s(const unsigned char* __restrict__ g8,
                                              const float2* __restrict__ csr,
                                              const int* __restrict__ rowptr,
                                              const int* __restrict__ csums,
                                              const float* __restrict__ dinv,
                                              const float* __restrict__ b2,
                                              const unsigned short* __restrict__ WT2,
                                              float* __restrict__ out, int N) {
    __shared__ unsigned short sA[16][136];
    const int lane = threadIdx.x & 63;
    const int wv   = threadIdx.x >> 6;
    const int q    = lane >> 4;     // quarter (== MFMA quad later)
    const int l    = lane & 15;
    const int nb   = blockIdx.x * 16;
    const int node = nb + wv * 4 + q;
    const uint2* G2 = (const uint2*)g8;

    // ---- phase 1: each quarter gathers its node (no bias, no act) ----
    float acc[8] = {};
    if (node < N) {
        const int start = rowptr[node] + csums[node >> 10];
        const int end   = rowptr[node + 1] + csums[(node + 1) >> 10];
        const float di = dinv[node];
        fma8_f8(acc, G2[(size_t)node * 16 + l], di * di);   // self-loop
        gather_q8(acc, G2, csr, start, end, l);
    }
    uint4 o = make_uint4(0u, 0u, 0u, 0u);   // zero rows for node >= N
    if (node < N) {
        o.x = (uint32)f2bf(acc[0]) | ((uint32)f2bf(acc[1]) << 16);
        o.y = (uint32)f2bf(acc[2]) | ((uint32)f2bf(acc[3]) << 16);
        o.z = (uint32)f2bf(acc[4]) | ((uint32)f2bf(acc[5]) << 16);
        o.w = (uint32)f2bf(acc[6]) | ((uint32)f2bf(acc[7]) << 16);
    }
    *(uint4*)&sA[wv * 4 + q][l * 8] = o;

    __syncthreads();

    // ---- phase 2: out[nb..nb+16) = sigmoid(sA @ W2 + b2), cols [wv*32,+32) ----
    f32x4 a2[2] = {};
    #pragma unroll
    for (int ks = 0; ks < 4; ++ks) {
        const int k0 = ks * 32 + q * 8;
        bf16x8 a = *(const bf16x8*)&sA[l][k0];
        #pragma unroll
        for (int ct = 0; ct < 2; ++ct) {
            bf16x8 b = *(const bf16x8*)(WT2 + (size_t)(wv * 32 + ct * 16 + l) * 128 + k0);
            a2[ct] = __builtin_amdgcn_mfma_f32_16x16x32_bf16(a, b, a2[ct], 0, 0, 0);
        }
    }
    // D layout: col (within 16-tile) = lane&15, row = q*4 + reg
    #pragma unroll
    for (int ct = 0; ct < 2; ++ct) {
        const int col = wv * 32 + ct * 16 + l;
        const float bb = b2[col];
        #pragma unroll
        for (int r = 0; r < 4; ++r) {
            int row = nb + q * 4 + r;
            if (row < N) {
                float v = a2[ct][r] + bb;
                out[(size_t)row * 128 + col] = 1.0f / (1.0f + expf(-v));
            }
        }
    }
}

extern "C" void kernel_launch(void* const* d_in, const int* in_sizes, int n_in,
                              void* d_out, int out_size, void* d_ws, size_t ws_size,
                              hipStream_t stream) {
    const float* x  = (const float*)d_in[0];
    const int*   ei = (const int*)d_in[1];
    const float* ew = (const float*)d_in[2];
    const float* W1 = (const float*)d_in[3];
    const float* b1 = (const float*)d_in[4];
    const float* W2 = (const float*)d_in[5];
    const float* b2 = (const float*)d_in[6];

    const int N = in_sizes[0] / 128;
    const int E = in_sizes[2];
    const int* src = ei;
    const int* dst = ei + E;
    float* out = (float*)d_out;

    // Workspace layout (256B-aligned slabs):
    //   dinv [N] | rowptr [N+1] | csums [1024] | done | bases [N u64]
    //   | WT1 | WT2 | rank [E] | csr [E f2] | h8 [N*128 fp8]
    //   | g8 [N*128 fp8]
    //   (packed u64[8N] aliases g8: dead after k_scan, g8 written at k_ag1;
    //    8N u64 = 3.2 MB < 6.4 MB g8 slab)
    auto align = [](size_t v) { return (v + 255) & ~(size_t)255; };
    char* p = (char*)d_ws;
    float*  dinv   = (float*)p;   p += align((size_t)N * 4);
    int*    rowptr = (int*)p;     p += align((size_t)(N + 1) * 4);
    int*    csums  = (int*)p;     p += align((size_t)1024 * 4);
    int*    done   = (int*)p;     p += align((size_t)256);
    u64*    bases  = (u64*)p;     p += align((size_t)N * 8);
    unsigned short* WT1 = (unsigned short*)p; p += align((size_t)128 * 128 * 2);
    unsigned short* WT2 = (unsigned short*)p; p += align((size_t)128 * 128 * 2);
    int*    rank   = (int*)p;     p += align((size_t)E * 4);
    float2* csr    = (float2*)p;  p += align((size_t)E * 8);
    unsigned char*  h8 = (unsigned char*)p;  p += align((size_t)N * 128);
    unsigned char*  g8 = (unsigned char*)p;
    u64* packed = (u64*)g8;  // alias (dead after scan; g8 written at ag1)

    const int nbE = (E + 255) / 256;
    const int gScan = (N + 1 + 1023) / 1024;   // 49 for N=50000 (<=64 required)
    const int gGemm = (N + 127) / 128;
    const int gAg1  = 2 * ((N + 15) / 16);     // x2: column halves (XCD-pinned)
    const int gAg2  = (N + 15) / 16;
    const int n4 = N * 4;                      // 8N u64 = 4N uint4
    const int gInit = ((n4 + 255) / 256) < 64 ? 64 : ((n4 + 255) / 256);

    // --- Build (+ layer-1 GEMM overlapped with hist) ---
    k_init<<<gInit, 256, 0, stream>>>(packed, n4, done, W1, W2, WT1, WT2);
    k_gemm1_hist<<<gGemm + nbE, 256, 0, stream>>>(x, WT1, h8, dst, ew, packed,
                                                  rank, E, N, gGemm);
    k_scan<<<gScan, 256, 0, stream>>>(packed, dinv, bases, rowptr, csums, done, N);
    k_fill<<<nbE, 256, 0, stream>>>(src, dst, ew, dinv, rowptr, csums, bases,
                                    rank, csr, E);

    // --- Layer 1: g8 = fp8(relu(agg(h8) + b1)), column-split + XCD-pinned ---
    k_ag1<<<gAg1, 256, 0, stream>>>(h8, csr, rowptr, csums, dinv,
                                    (const float4*)b1, g8, N);

    // --- Layer 2 fused: out = sigmoid(agg(g8) @ W2 + b2) ---
    k_ag2s<<<gAg2, 256, 0, stream>>>(g8, csr, rowptr, csums, dinv, b2,
                                     WT2, out, N);
}

// Round 10
// 190.502 us; speedup vs baseline: 1.0919x; 1.0073x over previous
//
#include <hip/hip_runtime.h>
#include <math.h>

// ---------------------------------------------------------------------------
// GCN 2-layer forward on MI355X.
// Round 21: R16 base (best measured 190.2; R17/R18/R19/R20 levers all null or
// regressed) + software-pipelined gathers:
//  (1) csr batch k+1 prefetched while batch k's random row loads are in
//      flight (hides the serial ~200-400cy csr round under row latency);
//  (2) per-edge index clamp dropped - csr padded with 16 zero-weight entries
//      past E (k_init writes them); out-of-row reads contribute exactly 0
//      via the kept w-mask;
//  (3) csr stores src*16 (uint2-row offset) - one less shift per row addr.
// Numerically identical accumulation (masked lanes add w=0 * finite = 0).
// ---------------------------------------------------------------------------

typedef unsigned int uint32;
typedef unsigned long long u64;
typedef __attribute__((ext_vector_type(8))) short bf16x8;   // 8 bf16 (4 VGPRs)
typedef __attribute__((ext_vector_type(4))) float f32x4;
typedef __attribute__((ext_vector_type(2))) float f32x2;

__device__ __forceinline__ unsigned short f2bf(float f) {   // RNE fp32->bf16
    uint32 b = __float_as_uint(f);
    return (unsigned short)((b + 0x7FFFu + ((b >> 16) & 1u)) >> 16);
}

// ---------------------------------------------------------------------------
// MFMA GEMM body: H[n x 128] = A[n x 128] @ W (WT bf16 transposed).
// 256 threads = 4 waves; each wave 32 rows x 128 cols (2x8 16x16 tiles),
// K=128 in 4 steps. AFP32: A fp32 (converted inline) vs bf16.
// OUTFP8: D written as fp8 e4m3 bytes vs bf16.
// ---------------------------------------------------------------------------
template <int AFP32, int OUTFP8>
__device__ __forceinline__ void gemm_body(const void* __restrict__ Ap,
                                          const unsigned short* __restrict__ WT,
                                          void* __restrict__ H,
                                          int n, int tb) {
    const int lane = threadIdx.x & 63;
    const int wv   = threadIdx.x >> 6;
    const int quad = lane >> 4;
    const int l16  = lane & 15;
    const int m0   = tb * 128 + wv * 32;
    f32x4 acc[2][8] = {};

    #pragma unroll
    for (int ks = 0; ks < 4; ++ks) {
        const int k0 = ks * 32 + quad * 8;
        bf16x8 a[2];
        #pragma unroll
        for (int rt = 0; rt < 2; ++rt) {
            int row = m0 + rt * 16 + l16;
            if (row >= n) row = n - 1;  // clamp; stores are guarded
            if (AFP32) {
                const float* Af = (const float*)Ap + (size_t)row * 128 + k0;
                float4 f0 = *(const float4*)(Af);
                float4 f1 = *(const float4*)(Af + 4);
                bf16x8 v;
                v[0] = (short)f2bf(f0.x); v[1] = (short)f2bf(f0.y);
                v[2] = (short)f2bf(f0.z); v[3] = (short)f2bf(f0.w);
                v[4] = (short)f2bf(f1.x); v[5] = (short)f2bf(f1.y);
                v[6] = (short)f2bf(f1.z); v[7] = (short)f2bf(f1.w);
                a[rt] = v;
            } else {
                const unsigned short* Ab = (const unsigned short*)Ap + (size_t)row * 128 + k0;
                a[rt] = *(const bf16x8*)Ab;
            }
        }
        #pragma unroll
        for (int ct = 0; ct < 8; ++ct) {
            bf16x8 b = *(const bf16x8*)(WT + (size_t)(ct * 16 + l16) * 128 + k0);
            acc[0][ct] = __builtin_amdgcn_mfma_f32_16x16x32_bf16(a[0], b, acc[0][ct], 0, 0, 0);
            acc[1][ct] = __builtin_amdgcn_mfma_f32_16x16x32_bf16(a[1], b, acc[1][ct], 0, 0, 0);
        }
    }

    // D layout: col = lane&15, row = quad*4 + reg  (m89-verified)
    #pragma unroll
    for (int rt = 0; rt < 2; ++rt) {
        #pragma unroll
        for (int r = 0; r < 4; ++r) {
            int row = m0 + rt * 16 + quad * 4 + r;
            if (row < n) {
                if (OUTFP8) {
                    unsigned char* o = (unsigned char*)H + (size_t)row * 128 + l16;
                    #pragma unroll
                    for (int cp = 0; cp < 4; ++cp) {
                        int pk = __builtin_amdgcn_cvt_pk_fp8_f32(
                            acc[rt][2 * cp][r], acc[rt][2 * cp + 1][r], 0, false);
                        o[(2 * cp) * 16]     = (unsigned char)(pk & 0xFF);
                        o[(2 * cp + 1) * 16] = (unsigned char)((pk >> 8) & 0xFF);
                    }
                } else {
                    unsigned short* o = (unsigned short*)H + (size_t)row * 128 + l16;
                    #pragma unroll
                    for (int ct = 0; ct < 8; ++ct)
                        o[ct * 16] = f2bf(acc[rt][ct][r]);
                }
            }
        }
    }
}

// ---------------------------------------------------------------------------
// Init: zero packed[8N u64] (as uint4) + done counter + 16 csr pad entries
// (src=0 pre-scaled, w=0); blocks [0,64) also transpose+convert W1/W2 to
// bf16 WT1/WT2.
// ---------------------------------------------------------------------------
__global__ __launch_bounds__(256) void k_init(u64* __restrict__ packed, int n4,
                                              int* __restrict__ done,
                                              float2* __restrict__ csr, int E,
                                              const float* __restrict__ W1,
                                              const float* __restrict__ W2,
                                              unsigned short* __restrict__ WT1,
                                              unsigned short* __restrict__ WT2) {
    int idx = blockIdx.x * 256 + threadIdx.x;
    if (idx < n4) ((uint4*)packed)[idx] = make_uint4(0u, 0u, 0u, 0u);
    if (idx == 0) *done = 0;
    if (idx < 16) csr[E + idx] = make_float2(0.0f, 0.0f);  // pad: row 0, w 0
    if (blockIdx.x < 64) {
        int j = blockIdx.x * 256 + threadIdx.x;  // 16384 total
        int k = j >> 7, nn = j & 127;
        WT1[nn * 128 + k] = f2bf(W1[k * 128 + nn]);
        WT2[nn * 128 + k] = f2bf(W2[k * 128 + nn]);
    }
}

// ---------------------------------------------------------------------------
// Fused gemm1 + hist: blocks [0,gGemm) compute h8 = fp8(x@W1) (MFMA pipe);
// blocks [gGemm, ...) do the 8-replica u64 histogram (atomic/TCC pipe).
// Replica r = (i>>8)&7, rank[i] = per-replica arrival order (atomic return).
// ---------------------------------------------------------------------------
__global__ __launch_bounds__(256) void k_gemm1_hist(const float* __restrict__ x,
                                                    const unsigned short* __restrict__ WT1,
                                                    unsigned char* __restrict__ h8,
                                                    const int* __restrict__ dst,
                                                    const float* __restrict__ ew,
                                                    u64* __restrict__ packed,
                                                    int* __restrict__ rank,
                                                    int E, int N, int gGemm) {
    const int b = blockIdx.x;
    if (b < gGemm) {
        gemm_body<1, 1>(x, WT1, h8, N, b);
        return;
    }
    int i = (b - gGemm) * 256 + threadIdx.x;
    if (i < E) {
        int d = dst[i];
        int r = (i >> 8) & 7;
        u64 add = (1ULL << 44) + (u64)(ew[i] * 4294967296.0f);
        u64 old = atomicAdd(&packed[(size_t)r * N + d], add);
        rank[i] = (int)(old >> 44);
    }
}

// ---------------------------------------------------------------------------
// Scan (one kernel): per-1024-chunk local exclusive scan of total counts into
// rowptr, fused decode (dinv, 8x8-bit replica bases), chunk totals release-
// stored into csums; last block (done counter) wave-scans the <=64 totals
// into exclusive chunk offsets in place.
// ---------------------------------------------------------------------------
__global__ __launch_bounds__(256) void k_scan(const u64* __restrict__ packed,
                                              float* __restrict__ dinv,
                                              u64* __restrict__ bases,
                                              int* __restrict__ rowptr,
                                              int* __restrict__ csums,
                                              int* __restrict__ done, int nNodes) {
    __shared__ int s[256];
    __shared__ int lastFlag;
    const int t = threadIdx.x;
    const int base = blockIdx.x * 1024 + t * 4;
    const int n = nNodes + 1;  // scan domain: N counts + trailing 0
    int v[4];
    #pragma unroll
    for (int u = 0; u < 4; ++u) {
        int idx = base + u;
        int c = 0;
        if (idx < nNodes) {
            const u64 mask = (1ULL << 44) - 1;
            u64 ssum = 0;
            u64 bs = 0;
            uint32 cum = 0;
            #pragma unroll
            for (int r = 0; r < 8; ++r) {
                u64 pv = packed[(size_t)r * nNodes + idx];
                bs |= (u64)cum << (8 * r);  // field 0 = 0
                cum += (uint32)(pv >> 44);
                ssum += (pv & mask);
            }
            c = (int)cum;
            float deg = 1.0f + (float)ssum * (1.0f / 4294967296.0f);
            dinv[idx] = rsqrtf(deg);
            bases[idx] = bs;
        }
        v[u] = c;
    }
    s[t] = v[0] + v[1] + v[2] + v[3];
    __syncthreads();
    #pragma unroll
    for (int off = 1; off < 256; off <<= 1) {
        int x = (t >= off) ? s[t - off] : 0;
        __syncthreads();
        s[t] += x;
        __syncthreads();
    }
    if (t == 255)
        __hip_atomic_store(&csums[blockIdx.x], s[255], __ATOMIC_RELEASE,
                           __HIP_MEMORY_SCOPE_AGENT);
    int e = (t == 0) ? 0 : s[t - 1];
    if (base + 0 < n) rowptr[base + 0] = e;
    if (base + 1 < n) rowptr[base + 1] = e + v[0];
    if (base + 2 < n) rowptr[base + 2] = e + v[0] + v[1];
    if (base + 3 < n) rowptr[base + 3] = e + v[0] + v[1] + v[2];

    // last-block: exclusive scan of the gridDim.x (<=64) chunk totals
    __syncthreads();  // all stores issued (incl. t255's release store)
    if (t == 0) {
        int prev = __hip_atomic_fetch_add(done, 1, __ATOMIC_ACQ_REL,
                                          __HIP_MEMORY_SCOPE_AGENT);
        lastFlag = (prev == (int)gridDim.x - 1);
    }
    __syncthreads();
    if (lastFlag && t < 64) {
        int g = (int)gridDim.x;
        int orig = (t < g) ? __hip_atomic_load(&csums[t], __ATOMIC_ACQUIRE,
                                               __HIP_MEMORY_SCOPE_AGENT)
                           : 0;
        int vv = orig;
        #pragma unroll
        for (int off = 1; off < 64; off <<= 1) {
            int y = __shfl_up(vv, off, 64);
            if (t >= off) vv += y;
        }
        if (t < g) csums[t] = vv - orig;  // exclusive chunk offset
    }
}

// Fill CSR (atomic-free):
//   pos = rowptr_local[d] + csums[d>>10] + base_replica(d, r) + rank[e].
// csr.x stores src*16 (uint2-row offset) to shave gather address math.
__global__ __launch_bounds__(256) void k_fill(const int* __restrict__ src,
                                              const int* __restrict__ dst,
                                              const float* __restrict__ ew,
                                              const float* __restrict__ dinv,
                                              const int* __restrict__ rowptr,
                                              const int* __restrict__ csums,
                                              const u64* __restrict__ bases,
                                              const int* __restrict__ rank,
                                              float2* __restrict__ csr, int e) {
    int i = blockIdx.x * 256 + threadIdx.x;
    if (i < e) {
        int s = src[i], d = dst[i];
        int r = (i >> 8) & 7;  // must match k_gemm1_hist's replica map
        float nrm = dinv[s] * ew[i] * dinv[d];
        int pos = rowptr[d] + csums[d >> 10]
                + (int)((bases[d] >> (8 * r)) & 0xFF) + rank[i];
        csr[pos] = make_float2(__int_as_float(s << 4), nrm);
    }
}

// ---------------------------------------------------------------------------
// CSR gather helper: 8-wide fp32 FMA from fp8 (uint2) rows.
// ---------------------------------------------------------------------------
__device__ __forceinline__ void fma8_f8(float* acc, uint2 u, float w) {
    f32x2 f;
    f = __builtin_amdgcn_cvt_pk_f32_fp8((int)u.x, false);
    acc[0] += f[0] * w; acc[1] += f[1] * w;
    f = __builtin_amdgcn_cvt_pk_f32_fp8((int)u.x, true);
    acc[2] += f[0] * w; acc[3] += f[1] * w;
    f = __builtin_amdgcn_cvt_pk_f32_fp8((int)u.y, false);
    acc[4] += f[0] * w; acc[5] += f[1] * w;
    f = __builtin_amdgcn_cvt_pk_f32_fp8((int)u.y, true);
    acc[6] += f[0] * w; acc[7] += f[1] * w;
}

// ---------------------------------------------------------------------------
// Per-quarter CSR edge walk, software-pipelined: batch k+1's csr entries are
// loaded while batch k's 8 random row loads are in flight (csr is padded
// with 16 zero-weight entries past E, so unclamped reads are safe; w-mask
// keeps out-of-row contributions at exactly 0). csr.x is pre-scaled src*16.
// ---------------------------------------------------------------------------
__device__ __forceinline__ void gather_q8p(float* acc, const uint2* __restrict__ T,
                                           const float2* __restrict__ csr,
                                           int start, int end, int l) {
    float2 c[8];
    #pragma unroll
    for (int j = 0; j < 8; ++j) c[j] = csr[start + j];   // padded-safe
    for (int k = start; k < end; k += 8) {
        uint2 u[8];
        float w[8];
        float2 cn[8];
        #pragma unroll
        for (int j = 0; j < 8; ++j) {
            w[j] = (k + j < end) ? c[j].y : 0.0f;
            u[j] = T[(size_t)(uint32)__float_as_int(c[j].x) + l];
        }
        #pragma unroll
        for (int j = 0; j < 8; ++j) cn[j] = csr[k + 8 + j];   // prefetch
        #pragma unroll
        for (int j = 0; j < 8; ++j) fma8_f8(acc, u[j], w[j]);
        #pragma unroll
        for (int j = 0; j < 8; ++j) c[j] = cn[j];
    }
}

// ---------------------------------------------------------------------------
// Layer-1 aggregation: g8 = fp8(relu(agg(h8) + b1)).
// Node-per-quarter: 16 nodes/block (4 waves x 4 quarters). Each quarter reads
// full fp8 rows (uint2 = 8 fp8/lane, 128 B row); no cross-lane reduction;
// all 64 lanes write (uint2 per lane, 4 node-rows per wave).
// ---------------------------------------------------------------------------
__global__ __launch_bounds__(256) void k_ag1(const unsigned char* __restrict__ h8,
                                             const float2* __restrict__ csr,
                                             const int* __restrict__ rowptr,
                                             const int* __restrict__ csums,
                                             const float* __restrict__ dinv,
                                             const float4* __restrict__ bias4,
                                             unsigned char* __restrict__ g8, int N) {
    const int lane = threadIdx.x & 63;
    const int q = lane >> 4, l = lane & 15;
    const int node = blockIdx.x * 16 + (threadIdx.x >> 6) * 4 + q;
    if (node >= N) return;   // lane-divergent ok: no barriers below
    const uint2* H2 = (const uint2*)h8;
    const int start = rowptr[node] + csums[node >> 10];
    const int end   = rowptr[node + 1] + csums[(node + 1) >> 10];
    const float di = dinv[node];

    float acc[8] = {};
    fma8_f8(acc, H2[(size_t)node * 16 + l], di * di);   // self-loop
    gather_q8p(acc, H2, csr, start, end, l);

    float4 b0 = bias4[l * 2], b1v = bias4[l * 2 + 1];
    acc[0] += b0.x;  acc[1] += b0.y;  acc[2] += b0.z;  acc[3] += b0.w;
    acc[4] += b1v.x; acc[5] += b1v.y; acc[6] += b1v.z; acc[7] += b1v.w;
    #pragma unroll
    for (int j = 0; j < 8; ++j) acc[j] = fmaxf(acc[j], 0.0f);
    uint2 o;
    int w0 = __builtin_amdgcn_cvt_pk_fp8_f32(acc[0], acc[1], 0, false);
    w0     = __builtin_amdgcn_cvt_pk_fp8_f32(acc[2], acc[3], w0, true);
    int w1 = __builtin_amdgcn_cvt_pk_fp8_f32(acc[4], acc[5], 0, false);
    w1     = __builtin_amdgcn_cvt_pk_fp8_f32(acc[6], acc[7], w1, true);
    o.x = (uint32)w0; o.y = (uint32)w1;
    ((uint2*)g8)[(size_t)node * 16 + l] = o;
}

// ---------------------------------------------------------------------------
// Layer-2 fused aggregate + GEMM + sigmoid (agg is linear: agg(g)@W2 ==
// agg(g@W2)). Block = 256 threads (4 waves) = 16 nodes, node-per-quarter.
// Phase 1: each quarter gathers its node over the fp8 g8 table (no bias/act),
// all lanes write bf16 rows into LDS sA[16][136] (pad 8 -> 2-way bank
// conflict = free). Phase 2: each wave computes the 16x32 col-slice of
// sA @ W2 at cols [wv*32,wv*32+32), adds b2, sigmoid, writes fp32 out.
// ---------------------------------------------------------------------------
__global__ __launch_bounds__(256) void k_ag2s(const unsigned char* __restrict__ g8,
                                              const float2* __restrict__ csr,
                                              const int* __restrict__ rowptr,
                                              const int* __restrict__ csums,
                                              const float* __restrict__ dinv,
                                              const float* __restrict__ b2,
                                              const unsigned short* __restrict__ WT2,
                                              float* __restrict__ out, int N) {
    __shared__ unsigned short sA[16][136];
    const int lane = threadIdx.x & 63;
    const int wv   = threadIdx.x >> 6;
    const int q    = lane >> 4;     // quarter (== MFMA quad later)
    const int l    = lane & 15;
    const int nb   = blockIdx.x * 16;
    const int node = nb + wv * 4 + q;
    const uint2* G2 = (const uint2*)g8;

    // ---- phase 1: each quarter gathers its node (no bias, no act) ----
    float acc[8] = {};
    if (node < N) {
        const int start = rowptr[node] + csums[node >> 10];
        const int end   = rowptr[node + 1] + csums[(node + 1) >> 10];
        const float di = dinv[node];
        fma8_f8(acc, G2[(size_t)node * 16 + l], di * di);   // self-loop
        gather_q8p(acc, G2, csr, start, end, l);
    }
    uint4 o = make_uint4(0u, 0u, 0u, 0u);   // zero rows for node >= N
    if (node < N) {
        o.x = (uint32)f2bf(acc[0]) | ((uint32)f2bf(acc[1]) << 16);
        o.y = (uint32)f2bf(acc[2]) | ((uint32)f2bf(acc[3]) << 16);
        o.z = (uint32)f2bf(acc[4]) | ((uint32)f2bf(acc[5]) << 16);
        o.w = (uint32)f2bf(acc[6]) | ((uint32)f2bf(acc[7]) << 16);
    }
    *(uint4*)&sA[wv * 4 + q][l * 8] = o;

    __syncthreads();

    // ---- phase 2: out[nb..nb+16) = sigmoid(sA @ W2 + b2), cols [wv*32,+32) ----
    f32x4 a2[2] = {};
    #pragma unroll
    for (int ks = 0; ks < 4; ++ks) {
        const int k0 = ks * 32 + q * 8;
        bf16x8 a = *(const bf16x8*)&sA[l][k0];
        #pragma unroll
        for (int ct = 0; ct < 2; ++ct) {
            bf16x8 b = *(const bf16x8*)(WT2 + (size_t)(wv * 32 + ct * 16 + l) * 128 + k0);
            a2[ct] = __builtin_amdgcn_mfma_f32_16x16x32_bf16(a, b, a2[ct], 0, 0, 0);
        }
    }
    // D layout: col (within 16-tile) = lane&15, row = q*4 + reg
    #pragma unroll
    for (int ct = 0; ct < 2; ++ct) {
        const int col = wv * 32 + ct * 16 + l;
        const float bb = b2[col];
        #pragma unroll
        for (int r = 0; r < 4; ++r) {
            int row = nb + q * 4 + r;
            if (row < N) {
                float v = a2[ct][r] + bb;
                out[(size_t)row * 128 + col] = 1.0f / (1.0f + expf(-v));
            }
        }
    }
}

extern "C" void kernel_launch(void* const* d_in, const int* in_sizes, int n_in,
                              void* d_out, int out_size, void* d_ws, size_t ws_size,
                              hipStream_t stream) {
    const float* x  = (const float*)d_in[0];
    const int*   ei = (const int*)d_in[1];
    const float* ew = (const float*)d_in[2];
    const float* W1 = (const float*)d_in[3];
    const float* b1 = (const float*)d_in[4];
    const float* W2 = (const float*)d_in[5];
    const float* b2 = (const float*)d_in[6];

    const int N = in_sizes[0] / 128;
    const int E = in_sizes[2];
    const int* src = ei;
    const int* dst = ei + E;
    float* out = (float*)d_out;

    // Workspace layout (256B-aligned slabs):
    //   dinv [N] | rowptr [N+1] | csums [1024] | done | bases [N u64]
    //   | WT1 | WT2 | rank [E] | csr [E+16 f2] | h8 [N*128 fp8]
    //   | g8 [N*128 fp8]
    //   (packed u64[8N] aliases g8: dead after k_scan, g8 written at k_ag1;
    //    8N u64 = 3.2 MB < 6.4 MB g8 slab)
    auto align = [](size_t v) { return (v + 255) & ~(size_t)255; };
    char* p = (char*)d_ws;
    float*  dinv   = (float*)p;   p += align((size_t)N * 4);
    int*    rowptr = (int*)p;     p += align((size_t)(N + 1) * 4);
    int*    csums  = (int*)p;     p += align((size_t)1024 * 4);
    int*    done   = (int*)p;     p += align((size_t)256);
    u64*    bases  = (u64*)p;     p += align((size_t)N * 8);
    unsigned short* WT1 = (unsigned short*)p; p += align((size_t)128 * 128 * 2);
    unsigned short* WT2 = (unsigned short*)p; p += align((size_t)128 * 128 * 2);
    int*    rank   = (int*)p;     p += align((size_t)E * 4);
    float2* csr    = (float2*)p;  p += align((size_t)(E + 16) * 8);
    unsigned char*  h8 = (unsigned char*)p;  p += align((size_t)N * 128);
    unsigned char*  g8 = (unsigned char*)p;
    u64* packed = (u64*)g8;  // alias (dead after scan; g8 written at ag1)

    const int nbE = (E + 255) / 256;
    const int gScan = (N + 1 + 1023) / 1024;   // 49 for N=50000 (<=64 required)
    const int gGemm = (N + 127) / 128;
    const int gAg1  = (N + 15) / 16;
    const int gAg2  = (N + 15) / 16;
    const int n4 = N * 4;                      // 8N u64 = 4N uint4
    const int gInit = ((n4 + 255) / 256) < 64 ? 64 : ((n4 + 255) / 256);

    // --- Build (+ layer-1 GEMM overlapped with hist) ---
    k_init<<<gInit, 256, 0, stream>>>(packed, n4, done, csr, E, W1, W2, WT1, WT2);
    k_gemm1_hist<<<gGemm + nbE, 256, 0, stream>>>(x, WT1, h8, dst, ew, packed,
                                                  rank, E, N, gGemm);
    k_scan<<<gScan, 256, 0, stream>>>(packed, dinv, bases, rowptr, csums, done, N);
    k_fill<<<nbE, 256, 0, stream>>>(src, dst, ew, dinv, rowptr, csums, bases,
                                    rank, csr, E);

    // --- Layer 1: g8 = fp8(relu(agg(h8) + b1)) ---
    k_ag1<<<gAg1, 256, 0, stream>>>(h8, csr, rowptr, csums, dinv,
                                    (const float4*)b1, g8, N);

    // --- Layer 2 fused: out = sigmoid(agg(g8) @ W2 + b2) ---
    k_ag2s<<<gAg2, 256, 0, stream>>>(g8, csr, rowptr, csums, dinv, b2,
                                     WT2, out, N);
}